// Round 6
// baseline (84.738 us; speedup 1.0000x reference)
//
#include <hip/hip_runtime.h>
#include <hip/hip_bf16.h>

#define PATCH 10
#define CELLS 1000   // 10*10*10
#define DPB   16     // depos per block (100000 % 16 == 0 -> 6250 blocks)

// 512 threads, 16 depos per block. R2 structure, PLAIN stores (A/B vs NT).
// Phase 1: threads 0..479 -> one (depo,dim,k) each: compute w[d][dim*10+k]
//          (2 erfs), k==0 threads also write offsets; dim0,k0 loads q.
// Phase 2: threads 0..499 -> 8 unrolled iterations; thread owns a fixed
//          float4 cell-group, iterates over depos. 32 KB of stores per block.
__global__ __launch_bounds__(512) void raster_kernel(
    const float* __restrict__ sigma,   // [N,3]
    const float* __restrict__ time,    // [N]
    const float* __restrict__ charge,  // [N]
    const float* __restrict__ tail,    // [N,3]
    const float* __restrict__ gs,      // [3]
    const float* __restrict__ nsig,    // [1]
    float* __restrict__ out_r,         // [N,10,10,10]
    float* __restrict__ out_off,       // [N,3] (int values stored as f32)
    int n)
{
    const int d0  = blockIdx.x * DPB;
    const int tid = threadIdx.x;

    __shared__ float wq[DPB][32];   // [d][0..29]=w, [30]=charge

    if (tid < DPB * 30) {
        const int d   = tid / 30;
        const int r   = tid - d * 30;
        const int dim = r / 10;
        const int k   = r - dim * 10;
        const int depo = d0 + d;
        if (depo < n) {
            float c;
            if (dim == 0)      c = tail[depo * 3 + 1];
            else if (dim == 1) c = tail[depo * 3 + 2];
            else               c = time[depo];
            const float sg = sigma[depo * 3 + dim];
            const float sp = gs[dim];
            const float ns = nsig[0];
            const float imin = floorf((c - ns * sg) / sp);
            const float inv  = 1.0f / (1.41421356237309f * sg);
            const float e0 = (imin + (float)k) * sp;
            const float cdf0 = 0.5f * (1.0f + erff((e0 - c) * inv));
            const float cdf1 = 0.5f * (1.0f + erff((e0 + sp - c) * inv));
            wq[d][dim * 10 + k] = cdf1 - cdf0;
            if (k == 0) {
                out_off[(size_t)depo * 3 + dim] = (float)(int)imin;
                if (dim == 0) wq[d][30] = charge[depo];
            }
        }
    }
    __syncthreads();

    if (tid < 500) {
        const int half = (tid >= 250) ? 1 : 0;
        const int c4   = tid - 250 * half;       // float4 index within depo
        const int cell0 = c4 * 4;

        // Per-component w indices, fixed for this thread across all depos.
        int a0[4], a1[4], a2[4];
#pragma unroll
        for (int c = 0; c < 4; ++c) {
            const int cell = cell0 + c;
            a0[c] = cell / 100;
            a1[c] = 10 + (cell / 10) % 10;
            a2[c] = 20 + cell % 10;
        }

#pragma unroll
        for (int it = 0; it < DPB / 2; ++it) {
            const int d    = it * 2 + half;
            const int depo = d0 + d;
            if (depo < n) {
                const float q = wq[d][30];
                float4 v;
                v.x = q * wq[d][a0[0]] * wq[d][a1[0]] * wq[d][a2[0]];
                v.y = q * wq[d][a0[1]] * wq[d][a1[1]] * wq[d][a2[1]];
                v.z = q * wq[d][a0[2]] * wq[d][a1[2]] * wq[d][a2[2]];
                v.w = q * wq[d][a0[3]] * wq[d][a1[3]] * wq[d][a2[3]];
                float4* dst = reinterpret_cast<float4*>(out_r + (size_t)depo * CELLS) + c4;
                *dst = v;   // plain store (A/B vs __builtin_nontemporal_store)
            }
        }
    }
}

extern "C" void kernel_launch(void* const* d_in, const int* in_sizes, int n_in,
                              void* d_out, int out_size, void* d_ws, size_t ws_size,
                              hipStream_t stream) {
    const float* sigma  = (const float*)d_in[0];  // [N,3]
    const float* time_  = (const float*)d_in[1];  // [N]
    const float* charge = (const float*)d_in[2];  // [N]
    const float* tail   = (const float*)d_in[3];  // [N,3]
    const float* gs     = (const float*)d_in[4];  // [3]
    const float* nsig   = (const float*)d_in[5];  // [1]

    const int n = in_sizes[1];  // time has N elements

    float* out_r   = (float*)d_out;                       // N*1000 floats
    float* out_off = (float*)d_out + (size_t)n * CELLS;   // N*3 values

    const int grid = (n + DPB - 1) / DPB;
    raster_kernel<<<grid, 512, 0, stream>>>(sigma, time_, charge, tail, gs, nsig,
                                            out_r, out_off, n);
}